// Round 15
// baseline (598.026 us; speedup 1.0000x reference)
//
#include <hip/hip_runtime.h>
#include <math.h>
#include <stdint.h>

#define BSZd 32
#define NTOK 243
#define DIMd 544
#define NH 8
#define HDd 68
#define NSEED 17
#define UPDd 1088
#define UCd 136
#define MROWS (BSZd*NTOK)          // 7776
#define BND ((size_t)MROWS*DIMd)   // 4230144
#define QPP 24576
#define KPOFF ((size_t)256*QPP)
#define VTP 20480
#define PBP 65536
#define BUFE (128*32)              // 128-tile LDS buffer (attn_pv2)
#define SLICE 6144                 // 64x32 A + 128x32 B elems per K-slice

typedef __bf16 bfx8 __attribute__((ext_vector_type(8)));
typedef __bf16 bfx4 __attribute__((ext_vector_type(4)));
typedef float  fx4  __attribute__((ext_vector_type(4)));

#define GLOAD_LDS(g, l) __builtin_amdgcn_global_load_lds( \
    (__attribute__((address_space(1))) void*)(g), \
    (__attribute__((address_space(3))) void*)(l), 16, 0, 0)

// ========== MFMA core, 128x128 tile, BK=32, 4 waves — double-buffered LDS ==========
// (used only by attn_pv2)
__device__ __forceinline__ void mfma_core(const __bf16* __restrict__ A, int lda,
        const __bf16* __restrict__ W, int ldb, int K,
        __bf16* __restrict__ As, __bf16* __restrict__ Bs, fx4 acc[4][4]) {
    const int tid = threadIdx.x;
    const int lane = tid & 63, wave = tid >> 6;
    const int r = lane >> 2, cp = lane & 3;
    const int c = cp ^ (r & 3) ^ ((r >> 2) & 1);
    const __bf16* Ag0 = A + (size_t)(wave * 32 + r) * lda + c * 8;
    const __bf16* Ag1 = Ag0 + (size_t)16 * lda;
    const __bf16* Wg0 = W + (size_t)(wave * 32 + r) * ldb + c * 8;
    const __bf16* Wg1 = Wg0 + (size_t)16 * ldb;
    const int wr0 = (wave * 32) * 32;
    const int wr1 = (wave * 32 + 16) * 32;
    const int fl = lane & 15, q = lane >> 4;
    const int wm = (wave & 1) * 64, wn = (wave >> 1) * 64;
    const int sw = (fl & 3) ^ ((fl >> 2) & 1);
    const int IT = K >> 5;
    GLOAD_LDS(Ag0, As + wr0);
    GLOAD_LDS(Ag1, As + wr1);
    GLOAD_LDS(Wg0, Bs + wr0);
    GLOAD_LDS(Wg1, Bs + wr1);
    for (int kit = 0; kit < IT; kit++) {
        const int p = kit & 1;
        __syncthreads();
        if (kit + 1 < IT) {
            const int np = 1 - p;
            const int off = (kit + 1) * 32;
            GLOAD_LDS(Ag0 + off, As + np * BUFE + wr0);
            GLOAD_LDS(Ag1 + off, As + np * BUFE + wr1);
            GLOAD_LDS(Wg0 + off, Bs + np * BUFE + wr0);
            GLOAD_LDS(Wg1 + off, Bs + np * BUFE + wr1);
        }
        const __bf16* Ab = As + p * BUFE;
        const __bf16* Bb = Bs + p * BUFE;
        bfx8 af[4], bfr[4];
        #pragma unroll
        for (int i = 0; i < 4; i++) {
            int m = wm + i * 16 + fl;
            af[i] = *(const bfx8*)(Ab + (m * 4 + (q ^ sw)) * 8);
            int n = wn + i * 16 + fl;
            bfr[i] = *(const bfx8*)(Bb + (n * 4 + (q ^ sw)) * 8);
        }
        #pragma unroll
        for (int i = 0; i < 4; i++)
            #pragma unroll
            for (int j = 0; j < 4; j++)
                acc[i][j] = __builtin_amdgcn_mfma_f32_16x16x32_bf16(af[i], bfr[j], acc[i][j], 0, 0, 0);
    }
}

// ================= PREP kernel: weight cvt + pad zeros + seed GEMMs w/ fused scatter ==
struct PrepArgs {
    const float* csrc[8];
    __bf16* cdst[8];
    int cnreal[8];
    int crows[8];
    int cK[8];
    const float* seed;
    const float* w0; const float* b0;
    const float* w1; const float* b1;
    __bf16* S0big; __bf16* S1bigT;
    __bf16* qp;       // Q/K panels base (Q at +0, K at +KPOFF)
    __bf16* vt;       // V panels base
    fx4* zS1pad; fx4* zMean;
};

__global__ __launch_bounds__(256) void prep(PrepArgs d) {
    int blk = blockIdx.x;
    const int tid = threadIdx.x;
    if (blk < 8704) {
        // ---- fp32 -> bf16 weight conversion (nt load: weights read exactly once) ----
        int seg = 0, base = 0;
        while (seg < 7 && blk - base >= d.crows[seg]) { base += d.crows[seg]; seg++; }
        int n = blk - base;
        int K = d.cK[seg];
        __bf16* drow = d.cdst[seg] + (size_t)n * K;
        if (n < d.cnreal[seg]) {
            const float* srow = d.csrc[seg] + (size_t)n * K;
            for (int k = tid * 4; k < K; k += 1024) {
                fx4 v = __builtin_nontemporal_load((const fx4*)(srow + k));
                bfx4 o; o[0]=(__bf16)v[0]; o[1]=(__bf16)v[1]; o[2]=(__bf16)v[2]; o[3]=(__bf16)v[3];
                *(bfx4*)(drow + k) = o;
            }
        } else {
            bfx4 z = {(__bf16)0.f,(__bf16)0.f,(__bf16)0.f,(__bf16)0.f};
            for (int k = tid * 4; k < K; k += 1024) *(bfx4*)(drow + k) = z;
        }
        return;
    }
    blk -= 8704;
    if (blk < 1024) {
        // ---- pad-only zero fills ----
        size_t tid0 = (size_t)blk * 256 + tid;   // 262144 threads
        bfx4 z4 = {(__bf16)0.f,(__bf16)0.f,(__bf16)0.f,(__bf16)0.f};
        bfx8 z8 = {(__bf16)0.f,(__bf16)0.f,(__bf16)0.f,(__bf16)0.f,
                   (__bf16)0.f,(__bf16)0.f,(__bf16)0.f,(__bf16)0.f};
        for (size_t id = tid0; id < 917504; id += 262144) {   // 2*256*256 rows * 7 chunks
            size_t row = id / 7; int k = (int)(id % 7);
            size_t sel = row >> 16;
            size_t bh  = (row >> 8) & 255;
            size_t tok = row & 255;
            __bf16* dst = d.qp + sel * KPOFF + bh * QPP + tok * 96 + 68 + k * 4;
            *(bfx4*)dst = z4;
        }
        for (size_t id = tid0; id < 40960; id += 262144) {    // 256 bh * 80 hd * 2 chunks
            size_t ch = id & 1, r = id >> 1;
            size_t bh = r / 80, hd = r % 80;
            __bf16* dst = d.vt + bh * VTP + hd * 256 + 240 + ch * 8;
            *(bfx8*)dst = z8;
        }
        fx4 z = {0.f, 0.f, 0.f, 0.f};
        for (size_t i = tid0; i < 1280; i += 262144) d.zS1pad[i] = z;
        for (size_t i = tid0; i < 136;  i += 262144) d.zMean[i] = z;
        return;
    }
    blk -= 1024;
    // ---- seed GEMMs (M=17, N=1088, K=544) with scatter fused into epilogue ----
    const int variant = blk / 17;                 // 0: s0->S0big, 1: s1->S1bigT
    const int n0 = (blk - variant * 17) * 64;
    const float* W    = variant ? d.w1 : d.w0;
    const float* bias = variant ? d.b1 : d.b0;
    __shared__ __align__(16) float As[16][68];
    __shared__ __align__(16) float Ws[16][68];
    __shared__ float stash[17][68];
    int tx = tid & 15, ty = tid >> 4;
    float acc[4][4] = {};
    int lr = tid >> 2, lk = (tid & 3) << 2;
    for (int k0 = 0; k0 < 544; k0 += 16) {
        float4 av = make_float4(0.f,0.f,0.f,0.f);
        float4 wv;
        int gk = k0 + lk;
        if (lr < 17) av = *(const float4*)(d.seed + (size_t)lr * 544 + gk);
        wv = *(const float4*)(W + (size_t)(n0 + lr) * 544 + gk);
        __syncthreads();
        As[lk+0][lr]=av.x; As[lk+1][lr]=av.y; As[lk+2][lr]=av.z; As[lk+3][lr]=av.w;
        Ws[lk+0][lr]=wv.x; Ws[lk+1][lr]=wv.y; Ws[lk+2][lr]=wv.z; Ws[lk+3][lr]=wv.w;
        __syncthreads();
        #pragma unroll
        for (int kk = 0; kk < 16; kk++) {
            float4 a4 = *(const float4*)&As[kk][ty << 2];
            float4 b4 = *(const float4*)&Ws[kk][tx << 2];
            float ar[4] = {a4.x, a4.y, a4.z, a4.w};
            float br[4] = {b4.x, b4.y, b4.z, b4.w};
            #pragma unroll
            for (int i = 0; i < 4; i++)
                #pragma unroll
                for (int j = 0; j < 4; j++)
                    acc[i][j] = fmaf(ar[i], br[j], acc[i][j]);
        }
    }
    #pragma unroll
    for (int i = 0; i < 4; i++) {
        int gm = (ty << 2) + i;
        if (gm < 17)
            #pragma unroll
            for (int j = 0; j < 4; j++)
                stash[gm][(tx << 2) + j] = acc[i][j] + bias[n0 + (tx << 2) + j];
    }
    __syncthreads();
    if (variant == 0) {
        for (int idx = tid; idx < 256 * 64; idx += 256) {
            int hn = idx >> 6, jo = idx & 63;
            int j = n0 + jo;
            int h = j / UCd;
            int dd = hn - h * NSEED;
            __bf16 v = (dd >= 0 && dd < NSEED) ? (__bf16)stash[dd][jo] : (__bf16)0.f;
            d.S0big[(size_t)hn * UPDd + j] = v;
        }
    } else {
        for (int idx = tid; idx < 64 * 160; idx += 256) {
            int jo = idx / 160, t = idx - jo * 160;
            int j = n0 + jo;
            int hj = j / UCd;
            int dd = t - hj * NSEED;
            __bf16 v = (dd >= 0 && dd < NSEED) ? (__bf16)stash[dd][jo] : (__bf16)0.f;
            d.S1bigT[(size_t)j * 160 + t] = v;
        }
    }
}

// ---------------- LayerNorm fp32 -> bf16 ----------------
__global__ __launch_bounds__(256) void ln_kernel(const float* __restrict__ x,
        const float* __restrict__ g, const float* __restrict__ bb, __bf16* __restrict__ out) {
    int row = blockIdx.x;
    const float* xr = x + (size_t)row * DIMd;
    __bf16* orow = out + (size_t)row * DIMd;
    int tid = threadIdx.x;
    float e0 = xr[tid];
    float e1 = xr[tid + 256];
    float e2 = (tid < DIMd - 512) ? xr[tid + 512] : 0.f;
    float s  = e0 + e1 + e2;
    float sq = e0*e0 + e1*e1 + e2*e2;
    __shared__ float sa[4], sb[4];
    for (int off = 32; off; off >>= 1) { s += __shfl_down(s, off, 64); sq += __shfl_down(sq, off, 64); }
    int lane = tid & 63, w = tid >> 6;
    if (lane == 0) { sa[w] = s; sb[w] = sq; }
    __syncthreads();
    if (tid == 0) { sa[0] = sa[0]+sa[1]+sa[2]+sa[3]; sb[0] = sb[0]+sb[1]+sb[2]+sb[3]; }
    __syncthreads();
    s = sa[0]; sq = sb[0];
    float mean = s * (1.f / DIMd);
    float var  = sq * (1.f / DIMd) - mean * mean;
    float rstd = rsqrtf(var + 1e-5f);
    orow[tid]       = (__bf16)((e0 - mean) * rstd * g[tid]       + bb[tid]);
    orow[tid + 256] = (__bf16)((e1 - mean) * rstd * g[tid + 256] + bb[tid + 256]);
    if (tid < DIMd - 512)
        orow[tid + 512] = (__bf16)((e2 - mean) * rstd * g[tid + 512] + bb[tid + 512]);
}

// ---------- MFMA GEMM (64x128 tile) — 8 waves, 3-buffer depth-1, MAX occupancy ----------
// TLP cap: 512 threads, 36KB LDS -> 4 blocks/CU = 32 waves/CU = 2048 thr/CU (HW max).
// Waves 0-3 stage; waves 4-7 pure consumers. Depth-1: issue slice kit+1, wait vmcnt(3)
// for slice kit (issued one iteration earlier); 4 independent blocks/CU provide the
// phase diversity to cover the exposed latency (the r14 TLP curve's next point).
// WAR-safe: buffers=3 >= depth+2; issue at kit targets (kit+1)%3=(kit-2)%3, whose last
// read compute(kit-2) precedes barrier kit-1 which precedes this issue.
template<int ACT, int HAS_BIAS, int HAS_RES, int OUTMODE>
__global__ __launch_bounds__(512) void mgemm(
        const __bf16* __restrict__ A, int lda, const __bf16* __restrict__ W, int ldb,
        const float* __restrict__ bias, const float* __restrict__ res,
        void* __restrict__ Cv, int M, int Mtiles, int Nreal, int K, int Cstride,
        __bf16* __restrict__ qQK, __bf16* __restrict__ qVt) {
    const int L = blockIdx.y * gridDim.x + blockIdx.x;
    const int xcd = L & 7, s = L >> 3;
    const int kk2 = s / gridDim.x, j2 = s - kk2 * gridDim.x;
    const int mt = kk2 * 8 + xcd;
    if (mt >= Mtiles) return;
    const int m0 = mt * 64, n0 = j2 * 128;
    __shared__ __bf16 Smem[3 * SLICE];          // 36KB: 3 bufs x [A 64x32 | B 128x32]
    const int tid = threadIdx.x, lane = tid & 63, w = tid >> 6;
    const int IT = K >> 5;                      // all call sites have IT >= 5
    const __bf16* Gs[3];
    int dbase[3];
    const bool prod = (w < 4);
    if (prod) {
        #pragma unroll
        for (int it = 0; it < 3; it++) {
            int ch = w * 192 + it * 64 + lane;
            int row = ch >> 2, cp2 = ch & 3;
            int cc = cp2 ^ (row & 3) ^ ((row >> 2) & 1);
            dbase[it] = (w * 192 + it * 64) * 8;    // wave-uniform LDS elem offset
            Gs[it] = (row < 64) ? A + (size_t)(m0 + row) * lda + cc * 8
                                : W + (size_t)(n0 + row - 64) * ldb + cc * 8;
        }
    }
    const int fl = lane & 15, q = lane >> 4;
    const int wm = (w & 1) * 32, wn = (w >> 1) * 32;   // 2x4 wave grid over 64x128
    const int sw = (fl & 3) ^ ((fl >> 2) & 1);
    fx4 acc[2][2];
    #pragma unroll
    for (int i = 0; i < 2; i++)
        #pragma unroll
        for (int j = 0; j < 2; j++)
            acc[i][j] = (fx4){0.f, 0.f, 0.f, 0.f};
    auto compute = [&](int pidx) {
        const __bf16* Ab = Smem + pidx * SLICE;
        const __bf16* Bb = Ab + 2048;
        bfx8 af[2], bfr[2];
        #pragma unroll
        for (int i = 0; i < 2; i++) {
            int m = wm + i * 16 + fl;
            af[i] = *(const bfx8*)(Ab + (m * 4 + (q ^ sw)) * 8);
        }
        #pragma unroll
        for (int j = 0; j < 2; j++) {
            int n = wn + j * 16 + fl;
            bfr[j] = *(const bfx8*)(Bb + (n * 4 + (q ^ sw)) * 8);
        }
        #pragma unroll
        for (int i = 0; i < 2; i++)
            #pragma unroll
            for (int j = 0; j < 2; j++)
                acc[i][j] = __builtin_amdgcn_mfma_f32_16x16x32_bf16(af[i], bfr[j], acc[i][j], 0, 0, 0);
    };
    // prologue: producers stage slice 0 (3 loads/lane outstanding)
    if (prod) {
        #pragma unroll
        for (int it = 0; it < 3; it++)
            GLOAD_LDS(Gs[it], Smem + dbase[it]);
    }
    int kit = 0;
    for (; kit < IT - 1; kit++) {
        if (prod) {
            const int koff = (kit + 1) * 32;
            __bf16* dst = Smem + ((kit + 1) % 3) * SLICE;
            #pragma unroll
            for (int it = 0; it < 3; it++)
                GLOAD_LDS(Gs[it] + koff, dst + dbase[it]);
            asm volatile("s_waitcnt vmcnt(3)" ::: "memory");   // slice kit landed
        }
        __builtin_amdgcn_s_barrier();
        __builtin_amdgcn_sched_barrier(0);
        compute(kit % 3);
    }
    if (prod) asm volatile("s_waitcnt vmcnt(0)" ::: "memory");
    __builtin_amdgcn_s_barrier();
    __builtin_amdgcn_sched_barrier(0);
    compute((IT - 1) % 3);
    #pragma unroll
    for (int i = 0; i < 2; i++)
        #pragma unroll
        for (int v = 0; v < 4; v++) {
            int row = m0 + wm + i * 16 + q * 4 + v;
            if (row >= M) continue;
            #pragma unroll
            for (int j = 0; j < 2; j++) {
                int col = n0 + wn + j * 16 + fl;
                if (col >= Nreal) continue;
                float val = acc[i][j][v];
                if (HAS_BIAS) val += bias[col];
                if (ACT == 1) val = 0.5f * val * (1.f + erff(val * 0.70710678118654752f));
                if (HAS_RES)  val += res[(size_t)row * Cstride + col];
                if (OUTMODE == 2) {
                    int t = col / DIMd, rem = col - t * DIMd;
                    int hh = rem / HDd, hd = rem - hh * HDd;
                    int b = row / NTOK, tok = row - b * NTOK;
                    int bh = b * 8 + hh;
                    if (t == 0)      qQK[(size_t)bh * QPP + tok * 96 + hd] = (__bf16)val;
                    else if (t == 1) qQK[KPOFF + (size_t)bh * QPP + tok * 96 + hd] = (__bf16)val;
                    else             qVt[(size_t)bh * VTP + hd * 256 + tok] = (__bf16)val;
                } else if (OUTMODE == 1) {
                    ((__bf16*)Cv)[(size_t)row * Cstride + col] = (__bf16)val;
                } else {
                    ((float*)Cv)[(size_t)row * Cstride + col] = val;
                }
            }
        }
}

// ================= ATTENTION kernel A: E = exp(QK^T*scale+bias), row sums =========
__global__ __launch_bounds__(256) void attn_escore(const __bf16* __restrict__ Qp,
        const float* __restrict__ bt, __bf16* __restrict__ Pb, float* __restrict__ rs) {
    __shared__ __bf16 Qs[128 * 96];
    __shared__ __bf16 Ks[256 * 96];
    __shared__ float sumb[128 * 2];
    const int mh = blockIdx.x, bh = blockIdx.y, h = bh & 7;
    const int tid = threadIdx.x, lane = tid & 63, w = tid >> 6;
    const int fl = lane & 15, q = lane >> 4;
    const int wm = (w & 1) * 64, wn = (w >> 1) * 128;
    const __bf16* Qg = Qp + (size_t)bh * QPP + (size_t)mh * 128 * 96;
    const __bf16* Kg = Qp + KPOFF + (size_t)bh * QPP;
    #pragma unroll
    for (int it = 0; it < 6; it++) {
        int Lc = (w * 6 + it) * 64 + lane;
        int r = Lc / 12, sl = Lc - r * 12, c = sl ^ (r & 3);
        GLOAD_LDS(Qg + r * 96 + c * 8, Qs + Lc * 8);
    }
    #pragma unroll
    for (int it = 0; it < 12; it++) {
        int Lc = (w * 12 + it) * 64 + lane;
        int r = Lc / 12, sl = Lc - r * 12, c = sl ^ (r & 3);
        GLOAD_LDS(Kg + r * 96 + c * 8, Ks + Lc * 8);
    }
    __syncthreads();
    fx4 acc[4][8];
    #pragma unroll
    for (int i = 0; i < 4; i++)
        #pragma unroll
        for (int jj = 0; jj < 8; jj++)
            acc[i][jj] = (fx4){0.f, 0.f, 0.f, 0.f};
    #pragma unroll
    for (int kk = 0; kk < 3; kk++) {
        bfx8 af[4], bfr[8];
        #pragma unroll
        for (int i = 0; i < 4; i++) {
            int rA = wm + i * 16 + fl, cA = kk * 4 + q;
            af[i] = *(const bfx8*)(Qs + (rA * 12 + (cA ^ (rA & 3))) * 8);
        }
        #pragma unroll
        for (int jj = 0; jj < 8; jj++) {
            int rB = wn + jj * 16 + fl, cB = kk * 4 + q;
            bfr[jj] = *(const bfx8*)(Ks + (rB * 12 + (cB ^ (rB & 3))) * 8);
        }
        #pragma unroll
        for (int i = 0; i < 4; i++)
            #pragma unroll
            for (int jj = 0; jj < 8; jj++)
                acc[i][jj] = __builtin_amdgcn_mfma_f32_16x16x32_bf16(af[i], bfr[jj], acc[i][jj], 0, 0, 0);
    }
    const float scale = 0.121267812518166f;
    const float* btr = bt + h * (2 * NTOK - 1);
    __bf16* Pp = Pb + (size_t)bh * PBP + (size_t)mh * 128 * 256;
    #pragma unroll
    for (int i = 0; i < 4; i++)
        #pragma unroll
        for (int v = 0; v < 4; v++) {
            int lr = wm + i * 16 + q * 4 + v;
            int gm = mh * 128 + lr;
            float sm = 0.f;
            #pragma unroll
            for (int jj = 0; jj < 8; jj++) {
                int gn = wn + jj * 16 + fl;
                float e = 0.f;
                if (gm < NTOK && gn < NTOK)
                    e = __expf(acc[i][jj][v] * scale + btr[gm - gn + NTOK - 1]);
                acc[i][jj][v] = e;
                sm += e;
                Pp[(size_t)lr * 256 + gn] = (__bf16)e;
            }
            #pragma unroll
            for (int msk = 1; msk < 16; msk <<= 1)
                sm += __shfl_xor(sm, msk, 64);
            if (fl == 0) sumb[lr * 2 + (w >> 1)] = sm;
        }
    __syncthreads();
    if (tid < 128)
        rs[(size_t)bh * 256 + mh * 128 + tid] = sumb[tid * 2] + sumb[tid * 2 + 1];
}

// ================= ATTENTION kernel B: O = (E @ V) / rowsum =================
__global__ __launch_bounds__(256) void attn_pv2(const __bf16* __restrict__ Pb,
        const __bf16* __restrict__ Vt, const float* __restrict__ rs,
        __bf16* __restrict__ o) {
    __shared__ __bf16 As[2 * BUFE];
    __shared__ __bf16 Bs[2 * BUFE];
    const int mt = blockIdx.x, bh = blockIdx.y, b = bh >> 3, h = bh & 7;
    const int tid = threadIdx.x, lane = tid & 63, wave = tid >> 6;
    fx4 acc[4][4];
    #pragma unroll
    for (int i = 0; i < 4; i++)
        #pragma unroll
        for (int j = 0; j < 4; j++)
            acc[i][j] = (fx4){0.f, 0.f, 0.f, 0.f};
    mfma_core(Pb + (size_t)bh * PBP + (size_t)mt * 128 * 256, 256,
              Vt + (size_t)bh * VTP, 256, 256, As, Bs, acc);
    const int fl = lane & 15, q = lane >> 4;
    const int wm = (wave & 1) * 64, wn = (wave >> 1) * 64;
    #pragma unroll
    for (int i = 0; i < 4; i++)
        #pragma unroll
        for (int v = 0; v < 4; v++) {
            int gm = mt * 128 + wm + i * 16 + q * 4 + v;
            if (gm >= NTOK) continue;
            float inv = 1.f / rs[(size_t)bh * 256 + gm];
            #pragma unroll
            for (int j = 0; j < 4; j++) {
                int col = wn + j * 16 + fl;
                if (col >= HDd) continue;
                o[((size_t)(b * NTOK + gm)) * DIMd + h * HDd + col] = (__bf16)(acc[i][j][v] * inv);
            }
        }
}

// seed: column softmax over f
__global__ __launch_bounds__(256) void seed_softmax2(float* __restrict__ a2) {
    int col = blockIdx.x, b = blockIdx.y;
    float* base = a2 + (size_t)b * NTOK * 136 + col;
    int f = threadIdx.x;
    __shared__ float rbuf[4];
    float v = (f < NTOK) ? base[(size_t)f * 136] : -1e30f;
    float m = v;
    for (int off = 32; off; off >>= 1) m = fmaxf(m, __shfl_down(m, off, 64));
    int lane = f & 63, w = f >> 6;
    if (lane == 0) rbuf[w] = m;
    __syncthreads();
    m = fmaxf(fmaxf(rbuf[0], rbuf[1]), fmaxf(rbuf[2], rbuf[3]));
    float e = (f < NTOK) ? __expf(v - m) : 0.f;
    float s = e;
    for (int off = 32; off; off >>= 1) s += __shfl_down(s, off, 64);
    __syncthreads();
    if (lane == 0) rbuf[w] = s;
    __syncthreads();
    float denom = rbuf[0] + rbuf[1] + rbuf[2] + rbuf[3];
    if (f < NTOK) base[(size_t)f * 136] = e / denom;
}

// seed: renorm over n per (b,f) -> bf16 a2b, per-b mean partials
__global__ __launch_bounds__(256) void seed_renorm(const float* __restrict__ a2,
        __bf16* __restrict__ a2b, float* __restrict__ part) {
    int f = blockIdx.x, b = blockIdx.y;
    int t = threadIdx.x;
    __shared__ float vals[136];
    __shared__ float hinv[8];
    __shared__ float nsum[NSEED];
    if (t < NSEED) nsum[t] = 0.f;
    const float* arow = a2 + ((size_t)(b * NTOK + f)) * 136;
    if (t < 136) vals[t] = arow[t];
    __syncthreads();
    if (t < 8) {
        float s = 0.f;
        #pragma unroll
        for (int n = 0; n < NSEED; n++) s += vals[t * NSEED + n];
        hinv[t] = 1.f / (1e-7f + s);
    }
    __syncthreads();
    __bf16* brow = a2b + ((size_t)(b * NTOK + f)) * 160;
    if (t < 160) {
        if (t < 136) {
            float wv = vals[t] * hinv[t / NSEED];
            brow[t] = (__bf16)wv;
            atomicAdd(&nsum[t % NSEED], wv);
        } else brow[t] = (__bf16)0.f;
    }
    __syncthreads();
    if (t < NSEED) atomicAdd(&part[b * NSEED + t], nsum[t]);
}

__global__ void mean_final(const float* __restrict__ part, float* __restrict__ mean_attn) {
    int n = threadIdx.x;
    if (n < NSEED) {
        float s = 0.f;
        for (int b = 0; b < BSZd; b++) s += part[b * NSEED + n];
        mean_attn[n] = s * (1.f / (BSZd * NH * NTOK));
    }
}

extern "C" void kernel_launch(void* const* d_in, const int* in_sizes, int n_in,
                              void* d_out, int out_size, void* d_ws, size_t ws_size,
                              hipStream_t stream) {
    (void)in_sizes; (void)n_in; (void)out_size; (void)ws_size;
    const float* x       = (const float*)d_in[0];
    const float* seed    = (const float*)d_in[1];
    const float* ln1_g   = (const float*)d_in[2];
    const float* ln1_b   = (const float*)d_in[3];
    const float* w_qkv   = (const float*)d_in[4];
    const float* w_proj  = (const float*)d_in[5];
    const float* b_proj  = (const float*)d_in[6];
    const float* b_table = (const float*)d_in[7];
    const float* ln2_g   = (const float*)d_in[8];
    const float* ln2_b   = (const float*)d_in[9];
    const float* mlp_w1  = (const float*)d_in[10];
    const float* mlp_b1  = (const float*)d_in[11];
    const float* mlp_w2  = (const float*)d_in[12];
    const float* mlp_b2  = (const float*)d_in[13];
    const float* eln1_g  = (const float*)d_in[14];
    const float* eln1_b  = (const float*)d_in[15];
    const float* w_trans = (const float*)d_in[16];
    const float* b_trans = (const float*)d_in[17];
    const float* w0      = (const float*)d_in[18];
    const float* b0      = (const float*)d_in[19];
    const float* w1      = (const float*)d_in[20];
    const float* b1      = (const float*)d_in[21];
    const float* w_proj2 = (const float*)d_in[22];
    const float* b_proj2 = (const float*)d_in[23];
    const float* eln2_g  = (const float*)d_in[24];
    const float* eln2_b  = (const float*)d_in[25];
    const float* emlp_w1 = (const float*)d_in[26];
    const float* emlp_b1 = (const float*)d_in[27];
    const float* emlp_w2 = (const float*)d_in[28];
    const float* emlp_b2 = (const float*)d_in[29];

    // ---- workspace layout (bytes) ----
    char* wsb = (char*)d_ws;
    __bf16* Wq  = (__bf16*)(wsb);               // [1664][544]
    __bf16* Wp  = (__bf16*)(wsb + 1810432);     // [640][544]
    __bf16* Wm1 = (__bf16*)(wsb + 2506752);     // [2176][544]
    __bf16* Wm2 = (__bf16*)(wsb + 4874240);     // [640][2176]
    __bf16* Wt  = (__bf16*)(wsb + 7659520);     // [1152][544]
    __bf16* Wp2 = (__bf16*)(wsb + 8912896);     // [640][1088]
    __bf16* We1 = (__bf16*)(wsb + 10305536);    // [1152][544]
    __bf16* We2 = (__bf16*)(wsb + 11558912);    // [640][1088]
    __bf16* Abf = (__bf16*)(wsb + 12951552);    // [7808][544]
    float*  F1  = (float*) (wsb + 21446656);    // [7776][544] fp32
    float*  F2  = (float*) (wsb + 38367232);    // [7776][544] fp32
    char*   RegBig = wsb + 55287808;            // 33,978,368 B
    char*   RegS   = wsb + 89266176;            // 15,178,752 B
    // attention overlays:
    __bf16* Qp  = (__bf16*)RegBig;              // Q/K panels
    __bf16* Pb  = (__bf16*)F1;                  // E panels (F1+F2)
    __bf16* Vt  = (__bf16*)RegS;                // V panels [0, 10485760)
    float*  rsb = (float*)(RegS + 10485760);    // rowsums [10485760, 10747904)
    // seed buffers — OUTSIDE the Vt overlay
    __bf16* S0big = (__bf16*)(RegS + 10747904); // [256][1088]  (557056 B)
    __bf16* S1bigT= (__bf16*)(RegS + 11304960); // [1152][160]  (368640 B)
    float*  mean_part = (float*)(RegS + 11673600); // 544 floats
    // other phase overlays:
    __bf16* Tb   = (__bf16*)RegBig;             // [7808][2176]
    __bf16* XU   = (__bf16*)RegBig;             // [7776][1088]
    __bf16* O2   = (__bf16*)(RegBig + 16920576);// [7808][1088]
    __bf16* T2   = (__bf16*)RegBig;             // [7808][1088]
    float*  a2    = (float*)RegS;               // [7776][136]
    __bf16* a2b   = (__bf16*)(RegS + 4230144);  // [7808][160]
    float* xout = (float*)d_out;
    float* mean_attn = xout + BND;

    dim3 blk(256);
    dim3 blk512(512);
    // 0) prep: weight cvt + pad-only zero fills + seed GEMMs (scatter fused)
    PrepArgs pa;
    pa.csrc[0]=w_qkv;  pa.cdst[0]=Wq;  pa.cnreal[0]=1632; pa.crows[0]=1664; pa.cK[0]=544;
    pa.csrc[1]=w_proj; pa.cdst[1]=Wp;  pa.cnreal[1]=544;  pa.crows[1]=640;  pa.cK[1]=544;
    pa.csrc[2]=mlp_w1; pa.cdst[2]=Wm1; pa.cnreal[2]=2176; pa.crows[2]=2176; pa.cK[2]=544;
    pa.csrc[3]=mlp_w2; pa.cdst[3]=Wm2; pa.cnreal[3]=544;  pa.crows[3]=640;  pa.cK[3]=2176;
    pa.csrc[4]=w_trans;pa.cdst[4]=Wt;  pa.cnreal[4]=1088; pa.crows[4]=1152; pa.cK[4]=544;
    pa.csrc[5]=w_proj2;pa.cdst[5]=Wp2; pa.cnreal[5]=544;  pa.crows[5]=640;  pa.cK[5]=1088;
    pa.csrc[6]=emlp_w1;pa.cdst[6]=We1; pa.cnreal[6]=1088; pa.crows[6]=1152; pa.cK[6]=544;
    pa.csrc[7]=emlp_w2;pa.cdst[7]=We2; pa.cnreal[7]=544;  pa.crows[7]=640;  pa.cK[7]=1088;
    pa.seed = seed; pa.w0 = w0; pa.b0 = b0; pa.w1 = w1; pa.b1 = b1;
    pa.S0big = S0big; pa.S1bigT = S1bigT;
    pa.qp = Qp; pa.vt = Vt;
    pa.zS1pad = (fx4*)(S1bigT + (size_t)1088 * 160);
    pa.zMean = (fx4*)mean_part;
    prep<<<9762, blk, 0, stream>>>(pa);
    // 1) h = LN1(x)
    ln_kernel<<<MROWS, blk, 0, stream>>>(x, ln1_g, ln1_b, Abf);
    // 2) qkv -> Qp/Kp/Vt panels   [64x128 tiles, 13 N-tiles x 122]
    mgemm<0,0,0,2><<<dim3(13,128), blk512, 0, stream>>>(Abf, 544, Wq, 544, nullptr, nullptr, nullptr, MROWS, 122, 1632, 544, 0, Qp, Vt);
    // 3) attention: E-score + PV
    attn_escore<<<dim3(2,256), blk, 0, stream>>>(Qp, b_table, Pb, rsb);
    attn_pv2<<<dim3(2,256), blk, 0, stream>>>(Pb, Vt, rsb, Abf);
    // 4) x1 = x + o @ w_proj^T + b_proj   [5 N-tiles]
    mgemm<0,1,1,0><<<dim3(5,128), blk512, 0, stream>>>(Abf, 544, Wp, 544, b_proj, x, F1, MROWS, 122, 544, 544, 544, nullptr, nullptr);
    // 5) h2 = LN2(x1)
    ln_kernel<<<MROWS, blk, 0, stream>>>(F1, ln2_g, ln2_b, Abf);
    // 6) t = gelu(h2 @ mlp_w1^T + b1)   [17 N-tiles]
    mgemm<1,1,0,1><<<dim3(17,128), blk512, 0, stream>>>(Abf, 544, Wm1, 544, mlp_b1, nullptr, Tb, MROWS, 122, 2176, 544, 2176, nullptr, nullptr);
    // 7) x2 = x1 + t @ mlp_w2^T + b2   [5 N-tiles, K=2176]
    mgemm<0,1,1,0><<<dim3(5,128), blk512, 0, stream>>>(Tb, 2176, Wm2, 2176, mlp_b2, F1, F2, MROWS, 122, 544, 2176, 544, nullptr, nullptr);
    // 8) h3 = eLN1(x2)
    ln_kernel<<<MROWS, blk, 0, stream>>>(F2, eln1_g, eln1_b, Abf);
    // 9) xu = h3 @ w_trans^T + b_trans   [9 N-tiles]
    mgemm<0,1,0,1><<<dim3(9,128), blk512, 0, stream>>>(Abf, 544, Wt, 544, b_trans, nullptr, XU, MROWS, 122, 1088, 544, 1088, nullptr, nullptr);
    // 12) a = XU @ S0big^T   [2 N-tiles, N=136]
    mgemm<0,0,0,0><<<dim3(2,128), blk512, 0, stream>>>(XU, 1088, S0big, 1088, nullptr, nullptr, a2, MROWS, 122, 136, 1088, 136, nullptr, nullptr);
    // 13) softmax over f
    seed_softmax2<<<dim3(136,BSZd), blk, 0, stream>>>(a2);
    // 15) renorm + mean partials (mean_part zeroed in prep)
    seed_renorm<<<dim3(NTOK,BSZd), blk, 0, stream>>>(a2, a2b, mean_part);
    mean_final<<<1, 32, 0, stream>>>(mean_part, mean_attn);
    // 16) o2 = a2b @ S1bigT^T   [9 N-tiles, K=160 -> IT=5]
    mgemm<0,0,0,1><<<dim3(9,128), blk512, 0, stream>>>(a2b, 160, S1bigT, 160, nullptr, nullptr, O2, MROWS, 122, 1088, 160, 1088, nullptr, nullptr);
    // 17) x3 = x2 + o2 @ w_proj2^T + b_proj2   [5 N-tiles, K=1088]
    mgemm<0,1,1,0><<<dim3(5,128), blk512, 0, stream>>>(O2, 1088, Wp2, 1088, b_proj2, F2, F1, MROWS, 122, 544, 1088, 544, nullptr, nullptr);
    // 18) h4 = eLN2(x3)
    ln_kernel<<<MROWS, blk, 0, stream>>>(F1, eln2_g, eln2_b, Abf);
    // 19) t2 = gelu(h4 @ emlp_w1^T + b1)   [9 N-tiles]
    mgemm<1,1,0,1><<<dim3(9,128), blk512, 0, stream>>>(Abf, 544, We1, 544, emlp_b1, nullptr, T2, MROWS, 122, 1088, 544, 1088, nullptr, nullptr);
    // 20) x4 = x3 + t2 @ emlp_w2^T + b2 -> d_out   [5 N-tiles, K=1088]
    mgemm<0,1,1,0><<<dim3(5,128), blk512, 0, stream>>>(T2, 1088, We2, 1088, emlp_b2, F1, xout, MROWS, 122, 544, 1088, 544, nullptr, nullptr);
}

// Round 17
// 589.270 us; speedup vs baseline: 1.0149x; 1.0149x over previous
//
#include <hip/hip_runtime.h>
#include <math.h>
#include <stdint.h>

#define BSZd 32
#define NTOK 243
#define DIMd 544
#define NH 8
#define HDd 68
#define NSEED 17
#define UPDd 1088
#define UCd 136
#define MROWS (BSZd*NTOK)          // 7776
#define BND ((size_t)MROWS*DIMd)   // 4230144
#define QPP 24576
#define KPOFF ((size_t)256*QPP)
#define VTP 20480
#define PBP 65536
#define BUFE (128*32)              // 128-tile LDS buffer (attn_pv2)
#define SLICE 6144                 // 64x32 A + 128x32 B elems per K-slice

typedef __bf16 bfx8 __attribute__((ext_vector_type(8)));
typedef __bf16 bfx4 __attribute__((ext_vector_type(4)));
typedef float  fx4  __attribute__((ext_vector_type(4)));

#define GLOAD_LDS(g, l) __builtin_amdgcn_global_load_lds( \
    (__attribute__((address_space(1))) void*)(g), \
    (__attribute__((address_space(3))) void*)(l), 16, 0, 0)

// ========== MFMA core, 128x128 tile, BK=32, 4 waves — double-buffered LDS ==========
// (used only by attn_pv2)
__device__ __forceinline__ void mfma_core(const __bf16* __restrict__ A, int lda,
        const __bf16* __restrict__ W, int ldb, int K,
        __bf16* __restrict__ As, __bf16* __restrict__ Bs, fx4 acc[4][4]) {
    const int tid = threadIdx.x;
    const int lane = tid & 63, wave = tid >> 6;
    const int r = lane >> 2, cp = lane & 3;
    const int c = cp ^ (r & 3) ^ ((r >> 2) & 1);
    const __bf16* Ag0 = A + (size_t)(wave * 32 + r) * lda + c * 8;
    const __bf16* Ag1 = Ag0 + (size_t)16 * lda;
    const __bf16* Wg0 = W + (size_t)(wave * 32 + r) * ldb + c * 8;
    const __bf16* Wg1 = Wg0 + (size_t)16 * ldb;
    const int wr0 = (wave * 32) * 32;
    const int wr1 = (wave * 32 + 16) * 32;
    const int fl = lane & 15, q = lane >> 4;
    const int wm = (wave & 1) * 64, wn = (wave >> 1) * 64;
    const int sw = (fl & 3) ^ ((fl >> 2) & 1);
    const int IT = K >> 5;
    GLOAD_LDS(Ag0, As + wr0);
    GLOAD_LDS(Ag1, As + wr1);
    GLOAD_LDS(Wg0, Bs + wr0);
    GLOAD_LDS(Wg1, Bs + wr1);
    for (int kit = 0; kit < IT; kit++) {
        const int p = kit & 1;
        __syncthreads();
        if (kit + 1 < IT) {
            const int np = 1 - p;
            const int off = (kit + 1) * 32;
            GLOAD_LDS(Ag0 + off, As + np * BUFE + wr0);
            GLOAD_LDS(Ag1 + off, As + np * BUFE + wr1);
            GLOAD_LDS(Wg0 + off, Bs + np * BUFE + wr0);
            GLOAD_LDS(Wg1 + off, Bs + np * BUFE + wr1);
        }
        const __bf16* Ab = As + p * BUFE;
        const __bf16* Bb = Bs + p * BUFE;
        bfx8 af[4], bfr[4];
        #pragma unroll
        for (int i = 0; i < 4; i++) {
            int m = wm + i * 16 + fl;
            af[i] = *(const bfx8*)(Ab + (m * 4 + (q ^ sw)) * 8);
            int n = wn + i * 16 + fl;
            bfr[i] = *(const bfx8*)(Bb + (n * 4 + (q ^ sw)) * 8);
        }
        #pragma unroll
        for (int i = 0; i < 4; i++)
            #pragma unroll
            for (int j = 0; j < 4; j++)
                acc[i][j] = __builtin_amdgcn_mfma_f32_16x16x32_bf16(af[i], bfr[j], acc[i][j], 0, 0, 0);
    }
}

// ================= PREP kernel: weight cvt + pad zeros + seed GEMMs w/ fused scatter ==
struct PrepArgs {
    const float* csrc[8];
    __bf16* cdst[8];
    int cnreal[8];
    int crows[8];
    int cK[8];
    const float* seed;
    const float* w0; const float* b0;
    const float* w1; const float* b1;
    __bf16* S0big; __bf16* S1bigT;
    __bf16* qp;       // Q/K panels base (Q at +0, K at +KPOFF)
    __bf16* vt;       // V panels base
    fx4* zS1pad; fx4* zMean;
};

__global__ __launch_bounds__(256) void prep(PrepArgs d) {
    int blk = blockIdx.x;
    const int tid = threadIdx.x;
    if (blk < 1024) {
        // ---- fp32 -> bf16 weight conversion: FLAT grid-stride, 128 blocks/segment ----
        // (row-major src/dst have identical flat layout over the real nreal*K region)
        int seg = blk >> 7, b = blk & 127;
        const fx4* src = (const fx4*)d.csrc[seg];
        bfx4* dst = (bfx4*)d.cdst[seg];
        int n4 = (d.cnreal[seg] * d.cK[seg]) >> 2;
        for (int idx = b * 256 + tid; idx < n4; idx += 32768) {
            fx4 v = __builtin_nontemporal_load(src + idx);
            bfx4 o; o[0]=(__bf16)v[0]; o[1]=(__bf16)v[1]; o[2]=(__bf16)v[2]; o[3]=(__bf16)v[3];
            dst[idx] = o;
        }
        return;
    }
    blk -= 1024;
    if (blk < 8) {
        // ---- pad-row zero fill (flat, 1 block/segment) ----
        int seg = blk;
        bfx4* dst = (bfx4*)(d.cdst[seg] + (size_t)d.cnreal[seg] * d.cK[seg]);
        int n4 = ((d.crows[seg] - d.cnreal[seg]) * d.cK[seg]) >> 2;
        bfx4 z = {(__bf16)0.f,(__bf16)0.f,(__bf16)0.f,(__bf16)0.f};
        for (int idx = tid; idx < n4; idx += 256) dst[idx] = z;
        return;
    }
    blk -= 8;
    if (blk < 1024) {
        // ---- pad-only zero fills for Q/K hd-pads, Vt tok-pads, S1 pad, mean ----
        size_t tid0 = (size_t)blk * 256 + tid;   // 262144 threads
        bfx4 z4 = {(__bf16)0.f,(__bf16)0.f,(__bf16)0.f,(__bf16)0.f};
        bfx8 z8 = {(__bf16)0.f,(__bf16)0.f,(__bf16)0.f,(__bf16)0.f,
                   (__bf16)0.f,(__bf16)0.f,(__bf16)0.f,(__bf16)0.f};
        for (size_t id = tid0; id < 917504; id += 262144) {   // 2*256*256 rows * 7 chunks
            size_t row = id / 7; int k = (int)(id % 7);
            size_t sel = row >> 16;
            size_t bh  = (row >> 8) & 255;
            size_t tok = row & 255;
            __bf16* dst = d.qp + sel * KPOFF + bh * QPP + tok * 96 + 68 + k * 4;
            *(bfx4*)dst = z4;
        }
        for (size_t id = tid0; id < 40960; id += 262144) {    // 256 bh * 80 hd * 2 chunks
            size_t ch = id & 1, r = id >> 1;
            size_t bh = r / 80, hd = r % 80;
            __bf16* dst = d.vt + bh * VTP + hd * 256 + 240 + ch * 8;
            *(bfx8*)dst = z8;
        }
        fx4 z = {0.f, 0.f, 0.f, 0.f};
        for (size_t i = tid0; i < 1280; i += 262144) d.zS1pad[i] = z;
        for (size_t i = tid0; i < 136;  i += 262144) d.zMean[i] = z;
        return;
    }
    blk -= 1024;
    // ---- seed GEMMs (M=17, N=1088, K=544) with scatter fused into epilogue ----
    const int variant = blk / 17;                 // 0: s0->S0big, 1: s1->S1bigT
    const int n0 = (blk - variant * 17) * 64;
    const float* W    = variant ? d.w1 : d.w0;
    const float* bias = variant ? d.b1 : d.b0;
    __shared__ __align__(16) float As[16][68];
    __shared__ __align__(16) float Ws[16][68];
    __shared__ float stash[17][68];
    int tx = tid & 15, ty = tid >> 4;
    float acc[4][4] = {};
    int lr = tid >> 2, lk = (tid & 3) << 2;
    for (int k0 = 0; k0 < 544; k0 += 16) {
        float4 av = make_float4(0.f,0.f,0.f,0.f);
        float4 wv;
        int gk = k0 + lk;
        if (lr < 17) av = *(const float4*)(d.seed + (size_t)lr * 544 + gk);
        wv = *(const float4*)(W + (size_t)(n0 + lr) * 544 + gk);
        __syncthreads();
        As[lk+0][lr]=av.x; As[lk+1][lr]=av.y; As[lk+2][lr]=av.z; As[lk+3][lr]=av.w;
        Ws[lk+0][lr]=wv.x; Ws[lk+1][lr]=wv.y; Ws[lk+2][lr]=wv.z; Ws[lk+3][lr]=wv.w;
        __syncthreads();
        #pragma unroll
        for (int kk = 0; kk < 16; kk++) {
            float4 a4 = *(const float4*)&As[kk][ty << 2];
            float4 b4 = *(const float4*)&Ws[kk][tx << 2];
            float ar[4] = {a4.x, a4.y, a4.z, a4.w};
            float br[4] = {b4.x, b4.y, b4.z, b4.w};
            #pragma unroll
            for (int i = 0; i < 4; i++)
                #pragma unroll
                for (int j = 0; j < 4; j++)
                    acc[i][j] = fmaf(ar[i], br[j], acc[i][j]);
        }
    }
    #pragma unroll
    for (int i = 0; i < 4; i++) {
        int gm = (ty << 2) + i;
        if (gm < 17)
            #pragma unroll
            for (int j = 0; j < 4; j++)
                stash[gm][(tx << 2) + j] = acc[i][j] + bias[n0 + (tx << 2) + j];
    }
    __syncthreads();
    if (variant == 0) {
        for (int idx = tid; idx < 256 * 64; idx += 256) {
            int hn = idx >> 6, jo = idx & 63;
            int j = n0 + jo;
            int h = j / UCd;
            int dd = hn - h * NSEED;
            __bf16 v = (dd >= 0 && dd < NSEED) ? (__bf16)stash[dd][jo] : (__bf16)0.f;
            d.S0big[(size_t)hn * UPDd + j] = v;
        }
    } else {
        for (int idx = tid; idx < 64 * 160; idx += 256) {
            int jo = idx / 160, t = idx - jo * 160;
            int j = n0 + jo;
            int hj = j / UCd;
            int dd = t - hj * NSEED;
            __bf16 v = (dd >= 0 && dd < NSEED) ? (__bf16)stash[dd][jo] : (__bf16)0.f;
            d.S1bigT[(size_t)j * 160 + t] = v;
        }
    }
}

// ---------------- LayerNorm fp32 -> bf16 ----------------
__global__ __launch_bounds__(256) void ln_kernel(const float* __restrict__ x,
        const float* __restrict__ g, const float* __restrict__ bb, __bf16* __restrict__ out) {
    int row = blockIdx.x;
    const float* xr = x + (size_t)row * DIMd;
    __bf16* orow = out + (size_t)row * DIMd;
    int tid = threadIdx.x;
    float e0 = xr[tid];
    float e1 = xr[tid + 256];
    float e2 = (tid < DIMd - 512) ? xr[tid + 512] : 0.f;
    float s  = e0 + e1 + e2;
    float sq = e0*e0 + e1*e1 + e2*e2;
    __shared__ float sa[4], sb[4];
    for (int off = 32; off; off >>= 1) { s += __shfl_down(s, off, 64); sq += __shfl_down(sq, off, 64); }
    int lane = tid & 63, w = tid >> 6;
    if (lane == 0) { sa[w] = s; sb[w] = sq; }
    __syncthreads();
    if (tid == 0) { sa[0] = sa[0]+sa[1]+sa[2]+sa[3]; sb[0] = sb[0]+sb[1]+sb[2]+sb[3]; }
    __syncthreads();
    s = sa[0]; sq = sb[0];
    float mean = s * (1.f / DIMd);
    float var  = sq * (1.f / DIMd) - mean * mean;
    float rstd = rsqrtf(var + 1e-5f);
    orow[tid]       = (__bf16)((e0 - mean) * rstd * g[tid]       + bb[tid]);
    orow[tid + 256] = (__bf16)((e1 - mean) * rstd * g[tid + 256] + bb[tid + 256]);
    if (tid < DIMd - 512)
        orow[tid + 512] = (__bf16)((e2 - mean) * rstd * g[tid + 512] + bb[tid + 512]);
}

// ---------- MFMA GEMM (64x128 tile) — 8 waves, producer/consumer, counted vmcnt ----------
// r14 config (best verified): 512 threads, 48KB LDS -> 3 blocks/CU = 24 waves/CU.
// Waves 0-3 stage with depth-2 prefetch + vmcnt(6); waves 4-7 pure consumers.
// WAR-safe: issue at iter kit targets buf (kit+2)&3 = (kit-2)&3, whose last reads
// (compute(kit-2), ALL waves) precede barrier kit-1, which precedes this issue.
template<int ACT, int HAS_BIAS, int HAS_RES, int OUTMODE>
__global__ __launch_bounds__(512) void mgemm(
        const __bf16* __restrict__ A, int lda, const __bf16* __restrict__ W, int ldb,
        const float* __restrict__ bias, const float* __restrict__ res,
        void* __restrict__ Cv, int M, int Mtiles, int Nreal, int K, int Cstride,
        __bf16* __restrict__ qQK, __bf16* __restrict__ qVt) {
    const int L = blockIdx.y * gridDim.x + blockIdx.x;
    const int xcd = L & 7, s = L >> 3;
    const int kk2 = s / gridDim.x, j2 = s - kk2 * gridDim.x;
    const int mt = kk2 * 8 + xcd;
    if (mt >= Mtiles) return;
    const int m0 = mt * 64, n0 = j2 * 128;
    __shared__ __bf16 Smem[4 * SLICE];          // 4 bufs x [A 64x32 | B 128x32]
    const int tid = threadIdx.x, lane = tid & 63, w = tid >> 6;
    const int IT = K >> 5;                      // all call sites have IT >= 5
    const __bf16* Gs[3];
    int dbase[3];
    const bool prod = (w < 4);
    if (prod) {
        #pragma unroll
        for (int it = 0; it < 3; it++) {
            int ch = w * 192 + it * 64 + lane;
            int row = ch >> 2, cp2 = ch & 3;
            int cc = cp2 ^ (row & 3) ^ ((row >> 2) & 1);
            dbase[it] = (w * 192 + it * 64) * 8;    // wave-uniform LDS elem offset
            Gs[it] = (row < 64) ? A + (size_t)(m0 + row) * lda + cc * 8
                                : W + (size_t)(n0 + row - 64) * ldb + cc * 8;
        }
    }
    const int fl = lane & 15, q = lane >> 4;
    const int wm = (w & 1) * 32, wn = (w >> 1) * 32;   // 2x4 wave grid over 64x128
    const int sw = (fl & 3) ^ ((fl >> 2) & 1);
    fx4 acc[2][2];
    #pragma unroll
    for (int i = 0; i < 2; i++)
        #pragma unroll
        for (int j = 0; j < 2; j++)
            acc[i][j] = (fx4){0.f, 0.f, 0.f, 0.f};
    auto compute = [&](int pidx) {
        const __bf16* Ab = Smem + pidx * SLICE;
        const __bf16* Bb = Ab + 2048;
        bfx8 af[2], bfr[2];
        #pragma unroll
        for (int i = 0; i < 2; i++) {
            int m = wm + i * 16 + fl;
            af[i] = *(const bfx8*)(Ab + (m * 4 + (q ^ sw)) * 8);
        }
        #pragma unroll
        for (int j = 0; j < 2; j++) {
            int n = wn + j * 16 + fl;
            bfr[j] = *(const bfx8*)(Bb + (n * 4 + (q ^ sw)) * 8);
        }
        #pragma unroll
        for (int i = 0; i < 2; i++)
            #pragma unroll
            for (int j = 0; j < 2; j++)
                acc[i][j] = __builtin_amdgcn_mfma_f32_16x16x32_bf16(af[i], bfr[j], acc[i][j], 0, 0, 0);
    };
    // prologue: producers stage slices 0,1  (6 loads/lane outstanding)
    if (prod) {
        #pragma unroll
        for (int sl = 0; sl < 2; sl++)
            #pragma unroll
            for (int it = 0; it < 3; it++)
                GLOAD_LDS(Gs[it] + sl * 32, Smem + sl * SLICE + dbase[it]);
    }
    int kit = 0;
    for (; kit < IT - 2; kit++) {
        if (prod) {
            const int koff = (kit + 2) * 32;
            __bf16* dst = Smem + ((kit + 2) & 3) * SLICE;
            #pragma unroll
            for (int it = 0; it < 3; it++)
                GLOAD_LDS(Gs[it] + koff, dst + dbase[it]);
            asm volatile("s_waitcnt vmcnt(6)" ::: "memory");   // slice kit landed
        }
        __builtin_amdgcn_s_barrier();
        __builtin_amdgcn_sched_barrier(0);
        compute(kit & 3);
    }
    if (prod) asm volatile("s_waitcnt vmcnt(3)" ::: "memory");
    __builtin_amdgcn_s_barrier();
    __builtin_amdgcn_sched_barrier(0);
    compute((IT - 2) & 3);
    if (prod) asm volatile("s_waitcnt vmcnt(0)" ::: "memory");
    __builtin_amdgcn_s_barrier();
    __builtin_amdgcn_sched_barrier(0);
    compute((IT - 1) & 3);
    #pragma unroll
    for (int i = 0; i < 2; i++)
        #pragma unroll
        for (int v = 0; v < 4; v++) {
            int row = m0 + wm + i * 16 + q * 4 + v;
            if (row >= M) continue;
            #pragma unroll
            for (int j = 0; j < 2; j++) {
                int col = n0 + wn + j * 16 + fl;
                if (col >= Nreal) continue;
                float val = acc[i][j][v];
                if (HAS_BIAS) val += bias[col];
                if (ACT == 1) val = 0.5f * val * (1.f + erff(val * 0.70710678118654752f));
                if (HAS_RES)  val += res[(size_t)row * Cstride + col];
                if (OUTMODE == 2) {
                    int t = col / DIMd, rem = col - t * DIMd;
                    int hh = rem / HDd, hd = rem - hh * HDd;
                    int b = row / NTOK, tok = row - b * NTOK;
                    int bh = b * 8 + hh;
                    if (t == 0)      qQK[(size_t)bh * QPP + tok * 96 + hd] = (__bf16)val;
                    else if (t == 1) qQK[KPOFF + (size_t)bh * QPP + tok * 96 + hd] = (__bf16)val;
                    else             qVt[(size_t)bh * VTP + hd * 256 + tok] = (__bf16)val;
                } else if (OUTMODE == 1) {
                    ((__bf16*)Cv)[(size_t)row * Cstride + col] = (__bf16)val;
                } else {
                    ((float*)Cv)[(size_t)row * Cstride + col] = val;
                }
            }
        }
}

// ================= ATTENTION kernel A: E = exp(QK^T*scale+bias), row sums =========
__global__ __launch_bounds__(256) void attn_escore(const __bf16* __restrict__ Qp,
        const float* __restrict__ bt, __bf16* __restrict__ Pb, float* __restrict__ rs) {
    __shared__ __bf16 Qs[128 * 96];
    __shared__ __bf16 Ks[256 * 96];
    __shared__ float sumb[128 * 2];
    const int mh = blockIdx.x, bh = blockIdx.y, h = bh & 7;
    const int tid = threadIdx.x, lane = tid & 63, w = tid >> 6;
    const int fl = lane & 15, q = lane >> 4;
    const int wm = (w & 1) * 64, wn = (w >> 1) * 128;
    const __bf16* Qg = Qp + (size_t)bh * QPP + (size_t)mh * 128 * 96;
    const __bf16* Kg = Qp + KPOFF + (size_t)bh * QPP;
    #pragma unroll
    for (int it = 0; it < 6; it++) {
        int Lc = (w * 6 + it) * 64 + lane;
        int r = Lc / 12, sl = Lc - r * 12, c = sl ^ (r & 3);
        GLOAD_LDS(Qg + r * 96 + c * 8, Qs + Lc * 8);
    }
    #pragma unroll
    for (int it = 0; it < 12; it++) {
        int Lc = (w * 12 + it) * 64 + lane;
        int r = Lc / 12, sl = Lc - r * 12, c = sl ^ (r & 3);
        GLOAD_LDS(Kg + r * 96 + c * 8, Ks + Lc * 8);
    }
    __syncthreads();
    fx4 acc[4][8];
    #pragma unroll
    for (int i = 0; i < 4; i++)
        #pragma unroll
        for (int jj = 0; jj < 8; jj++)
            acc[i][jj] = (fx4){0.f, 0.f, 0.f, 0.f};
    #pragma unroll
    for (int kk = 0; kk < 3; kk++) {
        bfx8 af[4], bfr[8];
        #pragma unroll
        for (int i = 0; i < 4; i++) {
            int rA = wm + i * 16 + fl, cA = kk * 4 + q;
            af[i] = *(const bfx8*)(Qs + (rA * 12 + (cA ^ (rA & 3))) * 8);
        }
        #pragma unroll
        for (int jj = 0; jj < 8; jj++) {
            int rB = wn + jj * 16 + fl, cB = kk * 4 + q;
            bfr[jj] = *(const bfx8*)(Ks + (rB * 12 + (cB ^ (rB & 3))) * 8);
        }
        #pragma unroll
        for (int i = 0; i < 4; i++)
            #pragma unroll
            for (int jj = 0; jj < 8; jj++)
                acc[i][jj] = __builtin_amdgcn_mfma_f32_16x16x32_bf16(af[i], bfr[jj], acc[i][jj], 0, 0, 0);
    }
    const float scale = 0.121267812518166f;
    const float* btr = bt + h * (2 * NTOK - 1);
    __bf16* Pp = Pb + (size_t)bh * PBP + (size_t)mh * 128 * 256;
    #pragma unroll
    for (int i = 0; i < 4; i++)
        #pragma unroll
        for (int v = 0; v < 4; v++) {
            int lr = wm + i * 16 + q * 4 + v;
            int gm = mh * 128 + lr;
            float sm = 0.f;
            #pragma unroll
            for (int jj = 0; jj < 8; jj++) {
                int gn = wn + jj * 16 + fl;
                float e = 0.f;
                if (gm < NTOK && gn < NTOK)
                    e = __expf(acc[i][jj][v] * scale + btr[gm - gn + NTOK - 1]);
                acc[i][jj][v] = e;
                sm += e;
                Pp[(size_t)lr * 256 + gn] = (__bf16)e;
            }
            #pragma unroll
            for (int msk = 1; msk < 16; msk <<= 1)
                sm += __shfl_xor(sm, msk, 64);
            if (fl == 0) sumb[lr * 2 + (w >> 1)] = sm;
        }
    __syncthreads();
    if (tid < 128)
        rs[(size_t)bh * 256 + mh * 128 + tid] = sumb[tid * 2] + sumb[tid * 2 + 1];
}

// ================= ATTENTION kernel B: O = (E @ V) / rowsum =================
__global__ __launch_bounds__(256) void attn_pv2(const __bf16* __restrict__ Pb,
        const __bf16* __restrict__ Vt, const float* __restrict__ rs,
        __bf16* __restrict__ o) {
    __shared__ __bf16 As[2 * BUFE];
    __shared__ __bf16 Bs[2 * BUFE];
    const int mt = blockIdx.x, bh = blockIdx.y, b = bh >> 3, h = bh & 7;
    const int tid = threadIdx.x, lane = tid & 63, wave = tid >> 6;
    fx4 acc[4][4];
    #pragma unroll
    for (int i = 0; i < 4; i++)
        #pragma unroll
        for (int j = 0; j < 4; j++)
            acc[i][j] = (fx4){0.f, 0.f, 0.f, 0.f};
    mfma_core(Pb + (size_t)bh * PBP + (size_t)mt * 128 * 256, 256,
              Vt + (size_t)bh * VTP, 256, 256, As, Bs, acc);
    const int fl = lane & 15, q = lane >> 4;
    const int wm = (wave & 1) * 64, wn = (wave >> 1) * 64;
    #pragma unroll
    for (int i = 0; i < 4; i++)
        #pragma unroll
        for (int v = 0; v < 4; v++) {
            int gm = mt * 128 + wm + i * 16 + q * 4 + v;
            if (gm >= NTOK) continue;
            float inv = 1.f / rs[(size_t)bh * 256 + gm];
            #pragma unroll
            for (int j = 0; j < 4; j++) {
                int col = wn + j * 16 + fl;
                if (col >= HDd) continue;
                o[((size_t)(b * NTOK + gm)) * DIMd + h * HDd + col] = (__bf16)(acc[i][j][v] * inv);
            }
        }
}

// seed: column softmax over f
__global__ __launch_bounds__(256) void seed_softmax2(float* __restrict__ a2) {
    int col = blockIdx.x, b = blockIdx.y;
    float* base = a2 + (size_t)b * NTOK * 136 + col;
    int f = threadIdx.x;
    __shared__ float rbuf[4];
    float v = (f < NTOK) ? base[(size_t)f * 136] : -1e30f;
    float m = v;
    for (int off = 32; off; off >>= 1) m = fmaxf(m, __shfl_down(m, off, 64));
    int lane = f & 63, w = f >> 6;
    if (lane == 0) rbuf[w] = m;
    __syncthreads();
    m = fmaxf(fmaxf(rbuf[0], rbuf[1]), fmaxf(rbuf[2], rbuf[3]));
    float e = (f < NTOK) ? __expf(v - m) : 0.f;
    float s = e;
    for (int off = 32; off; off >>= 1) s += __shfl_down(s, off, 64);
    __syncthreads();
    if (lane == 0) rbuf[w] = s;
    __syncthreads();
    float denom = rbuf[0] + rbuf[1] + rbuf[2] + rbuf[3];
    if (f < NTOK) base[(size_t)f * 136] = e / denom;
}

// seed: renorm over n per (b,f) -> bf16 a2b, per-b mean partials
__global__ __launch_bounds__(256) void seed_renorm(const float* __restrict__ a2,
        __bf16* __restrict__ a2b, float* __restrict__ part) {
    int f = blockIdx.x, b = blockIdx.y;
    int t = threadIdx.x;
    __shared__ float vals[136];
    __shared__ float hinv[8];
    __shared__ float nsum[NSEED];
    if (t < NSEED) nsum[t] = 0.f;
    const float* arow = a2 + ((size_t)(b * NTOK + f)) * 136;
    if (t < 136) vals[t] = arow[t];
    __syncthreads();
    if (t < 8) {
        float s = 0.f;
        #pragma unroll
        for (int n = 0; n < NSEED; n++) s += vals[t * NSEED + n];
        hinv[t] = 1.f / (1e-7f + s);
    }
    __syncthreads();
    __bf16* brow = a2b + ((size_t)(b * NTOK + f)) * 160;
    if (t < 160) {
        if (t < 136) {
            float wv = vals[t] * hinv[t / NSEED];
            brow[t] = (__bf16)wv;
            atomicAdd(&nsum[t % NSEED], wv);
        } else brow[t] = (__bf16)0.f;
    }
    __syncthreads();
    if (t < NSEED) atomicAdd(&part[b * NSEED + t], nsum[t]);
}

__global__ void mean_final(const float* __restrict__ part, float* __restrict__ mean_attn) {
    int n = threadIdx.x;
    if (n < NSEED) {
        float s = 0.f;
        for (int b = 0; b < BSZd; b++) s += part[b * NSEED + n];
        mean_attn[n] = s * (1.f / (BSZd * NH * NTOK));
    }
}

extern "C" void kernel_launch(void* const* d_in, const int* in_sizes, int n_in,
                              void* d_out, int out_size, void* d_ws, size_t ws_size,
                              hipStream_t stream) {
    (void)in_sizes; (void)n_in; (void)out_size; (void)ws_size;
    const float* x       = (const float*)d_in[0];
    const float* seed    = (const float*)d_in[1];
    const float* ln1_g   = (const float*)d_in[2];
    const float* ln1_b   = (const float*)d_in[3];
    const float* w_qkv   = (const float*)d_in[4];
    const float* w_proj  = (const float*)d_in[5];
    const float* b_proj  = (const float*)d_in[6];
    const float* b_table = (const float*)d_in[7];
    const float* ln2_g   = (const float*)d_in[8];
    const float* ln2_b   = (const float*)d_in[9];
    const float* mlp_w1  = (const float*)d_in[10];
    const float* mlp_b1  = (const float*)d_in[11];
    const float* mlp_w2  = (const float*)d_in[12];
    const float* mlp_b2  = (const float*)d_in[13];
    const float* eln1_g  = (const float*)d_in[14];
    const float* eln1_b  = (const float*)d_in[15];
    const float* w_trans = (const float*)d_in[16];
    const float* b_trans = (const float*)d_in[17];
    const float* w0      = (const float*)d_in[18];
    const float* b0      = (const float*)d_in[19];
    const float* w1      = (const float*)d_in[20];
    const float* b1      = (const float*)d_in[21];
    const float* w_proj2 = (const float*)d_in[22];
    const float* b_proj2 = (const float*)d_in[23];
    const float* eln2_g  = (const float*)d_in[24];
    const float* eln2_b  = (const float*)d_in[25];
    const float* emlp_w1 = (const float*)d_in[26];
    const float* emlp_b1 = (const float*)d_in[27];
    const float* emlp_w2 = (const float*)d_in[28];
    const float* emlp_b2 = (const float*)d_in[29];

    // ---- workspace layout (bytes) ----
    char* wsb = (char*)d_ws;
    __bf16* Wq  = (__bf16*)(wsb);               // [1664][544]
    __bf16* Wp  = (__bf16*)(wsb + 1810432);     // [640][544]
    __bf16* Wm1 = (__bf16*)(wsb + 2506752);     // [2176][544]
    __bf16* Wm2 = (__bf16*)(wsb + 4874240);     // [640][2176]
    __bf16* Wt  = (__bf16*)(wsb + 7659520);     // [1152][544]
    __bf16* Wp2 = (__bf16*)(wsb + 8912896);     // [640][1088]
    __bf16* We1 = (__bf16*)(wsb + 10305536);    // [1152][544]
    __bf16* We2 = (__bf16*)(wsb + 11558912);    // [640][1088]
    __bf16* Abf = (__bf16*)(wsb + 12951552);    // [7808][544]
    float*  F1  = (float*) (wsb + 21446656);    // [7776][544] fp32
    float*  F2  = (float*) (wsb + 38367232);    // [7776][544] fp32
    char*   RegBig = wsb + 55287808;            // 33,978,368 B
    char*   RegS   = wsb + 89266176;            // 15,178,752 B
    // attention overlays:
    __bf16* Qp  = (__bf16*)RegBig;              // Q/K panels
    __bf16* Pb  = (__bf16*)F1;                  // E panels (F1+F2)
    __bf16* Vt  = (__bf16*)RegS;                // V panels [0, 10485760)
    float*  rsb = (float*)(RegS + 10485760);    // rowsums [10485760, 10747904)
    // seed buffers — OUTSIDE the Vt overlay
    __bf16* S0big = (__bf16*)(RegS + 10747904); // [256][1088]  (557056 B)
    __bf16* S1bigT= (__bf16*)(RegS + 11304960); // [1152][160]  (368640 B)
    float*  mean_part = (float*)(RegS + 11673600); // 544 floats
    // other phase overlays:
    __bf16* Tb   = (__bf16*)RegBig;             // [7808][2176]
    __bf16* XU   = (__bf16*)RegBig;             // [7776][1088]
    __bf16* O2   = (__bf16*)(RegBig + 16920576);// [7808][1088]
    __bf16* T2   = (__bf16*)RegBig;             // [7808][1088]
    float*  a2    = (float*)RegS;               // [7776][136]
    __bf16* a2b   = (__bf16*)(RegS + 4230144);  // [7808][160]
    float* xout = (float*)d_out;
    float* mean_attn = xout + BND;

    dim3 blk(256);
    dim3 blk512(512);
    // 0) prep: flat weight cvt + pad-only zero fills + seed GEMMs (scatter fused)
    PrepArgs pa;
    pa.csrc[0]=w_qkv;  pa.cdst[0]=Wq;  pa.cnreal[0]=1632; pa.crows[0]=1664; pa.cK[0]=544;
    pa.csrc[1]=w_proj; pa.cdst[1]=Wp;  pa.cnreal[1]=544;  pa.crows[1]=640;  pa.cK[1]=544;
    pa.csrc[2]=mlp_w1; pa.cdst[2]=Wm1; pa.cnreal[2]=2176; pa.crows[2]=2176; pa.cK[2]=544;
    pa.csrc[3]=mlp_w2; pa.cdst[3]=Wm2; pa.cnreal[3]=544;  pa.crows[3]=640;  pa.cK[3]=2176;
    pa.csrc[4]=w_trans;pa.cdst[4]=Wt;  pa.cnreal[4]=1088; pa.crows[4]=1152; pa.cK[4]=544;
    pa.csrc[5]=w_proj2;pa.cdst[5]=Wp2; pa.cnreal[5]=544;  pa.crows[5]=640;  pa.cK[5]=1088;
    pa.csrc[6]=emlp_w1;pa.cdst[6]=We1; pa.cnreal[6]=1088; pa.crows[6]=1152; pa.cK[6]=544;
    pa.csrc[7]=emlp_w2;pa.cdst[7]=We2; pa.cnreal[7]=544;  pa.crows[7]=640;  pa.cK[7]=1088;
    pa.seed = seed; pa.w0 = w0; pa.b0 = b0; pa.w1 = w1; pa.b1 = b1;
    pa.S0big = S0big; pa.S1bigT = S1bigT;
    pa.qp = Qp; pa.vt = Vt;
    pa.zS1pad = (fx4*)(S1bigT + (size_t)1088 * 160);
    pa.zMean = (fx4*)mean_part;
    prep<<<2090, blk, 0, stream>>>(pa);
    // 1) h = LN1(x)
    ln_kernel<<<MROWS, blk, 0, stream>>>(x, ln1_g, ln1_b, Abf);
    // 2) qkv -> Qp/Kp/Vt panels   [64x128 tiles, 13 N-tiles x 122]
    mgemm<0,0,0,2><<<dim3(13,128), blk512, 0, stream>>>(Abf, 544, Wq, 544, nullptr, nullptr, nullptr, MROWS, 122, 1632, 544, 0, Qp, Vt);
    // 3) attention: E-score + PV
    attn_escore<<<dim3(2,256), blk, 0, stream>>>(Qp, b_table, Pb, rsb);
    attn_pv2<<<dim3(2,256), blk, 0, stream>>>(Pb, Vt, rsb, Abf);
    // 4) x1 = x + o @ w_proj^T + b_proj   [5 N-tiles]
    mgemm<0,1,1,0><<<dim3(5,128), blk512, 0, stream>>>(Abf, 544, Wp, 544, b_proj, x, F1, MROWS, 122, 544, 544, 544, nullptr, nullptr);
    // 5) h2 = LN2(x1)
    ln_kernel<<<MROWS, blk, 0, stream>>>(F1, ln2_g, ln2_b, Abf);
    // 6) t = gelu(h2 @ mlp_w1^T + b1)   [17 N-tiles]
    mgemm<1,1,0,1><<<dim3(17,128), blk512, 0, stream>>>(Abf, 544, Wm1, 544, mlp_b1, nullptr, Tb, MROWS, 122, 2176, 544, 2176, nullptr, nullptr);
    // 7) x2 = x1 + t @ mlp_w2^T + b2   [5 N-tiles, K=2176]
    mgemm<0,1,1,0><<<dim3(5,128), blk512, 0, stream>>>(Tb, 2176, Wm2, 2176, mlp_b2, F1, F2, MROWS, 122, 544, 2176, 544, nullptr, nullptr);
    // 8) h3 = eLN1(x2)
    ln_kernel<<<MROWS, blk, 0, stream>>>(F2, eln1_g, eln1_b, Abf);
    // 9) xu = h3 @ w_trans^T + b_trans   [9 N-tiles]
    mgemm<0,1,0,1><<<dim3(9,128), blk512, 0, stream>>>(Abf, 544, Wt, 544, b_trans, nullptr, XU, MROWS, 122, 1088, 544, 1088, nullptr, nullptr);
    // 12) a = XU @ S0big^T   [2 N-tiles, N=136]
    mgemm<0,0,0,0><<<dim3(2,128), blk512, 0, stream>>>(XU, 1088, S0big, 1088, nullptr, nullptr, a2, MROWS, 122, 136, 1088, 136, nullptr, nullptr);
    // 13) softmax over f
    seed_softmax2<<<dim3(136,BSZd), blk, 0, stream>>>(a2);
    // 15) renorm + mean partials (mean_part zeroed in prep)
    seed_renorm<<<dim3(NTOK,BSZd), blk, 0, stream>>>(a2, a2b, mean_part);
    mean_final<<<1, 32, 0, stream>>>(mean_part, mean_attn);
    // 16) o2 = a2b @ S1bigT^T   [9 N-tiles, K=160 -> IT=5]
    mgemm<0,0,0,1><<<dim3(9,128), blk512, 0, stream>>>(a2b, 160, S1bigT, 160, nullptr, nullptr, O2, MROWS, 122, 1088, 160, 1088, nullptr, nullptr);
    // 17) x3 = x2 + o2 @ w_proj2^T + b_proj2   [5 N-tiles, K=1088]
    mgemm<0,1,1,0><<<dim3(5,128), blk512, 0, stream>>>(O2, 1088, Wp2, 1088, b_proj2, F2, F1, MROWS, 122, 544, 1088, 544, nullptr, nullptr);
    // 18) h4 = eLN2(x3)
    ln_kernel<<<MROWS, blk, 0, stream>>>(F1, eln2_g, eln2_b, Abf);
    // 19) t2 = gelu(h4 @ emlp_w1^T + b1)   [9 N-tiles]
    mgemm<1,1,0,1><<<dim3(9,128), blk512, 0, stream>>>(Abf, 544, We1, 544, emlp_b1, nullptr, T2, MROWS, 122, 1088, 544, 1088, nullptr, nullptr);
    // 20) x4 = x3 + t2 @ emlp_w2^T + b2 -> d_out   [5 N-tiles, K=1088]
    mgemm<0,1,1,0><<<dim3(5,128), blk512, 0, stream>>>(T2, 1088, We2, 1088, emlp_b2, F1, xout, MROWS, 122, 544, 1088, 544, nullptr, nullptr);
}